// Round 1
// 482.752 us; speedup vs baseline: 1.2618x; 1.2618x over previous
//
#include <hip/hip_runtime.h>
#include <hip/hip_bf16.h>
#include <cstdint>
#include <cmath>

// Gemma3 attention, MI355X/gfx950.  Round 7: 256x256 8-phase GEMM (T2+T3+T4+T5)
// for the big matmuls: fused QKV projection (M=4096,N=4096,K=2560, 256 blocks)
// and O-proj (M=4096,N=2560,K=2048).  Attention-inner GEMMs keep the proven
// 128^2 structure.  Softcap tanh switched to __expf form.
// B=2, L=2048, H=2560, Hq=8, Hkv=4, D=256, window = last 512 keys.
// Workspace 75.5 MB:
//   [0,21.0M)   xb (4096x2560 bf16)     -> sc (4x2048x512 fp32) after projs
//   [21.0,41.9) qkvwb (4096x2560 bf16: q|k|v rows) ; rows 0-2047 -> owb after QKV
//   [41.9,58.7) q_ws (4096x2048) [attn aliases]   [58.7,67.1) k_ws
//   [67.1,75.5) vT ((b,kvh,d) x 2048)

using bf16 = __hip_bfloat16;
typedef __attribute__((ext_vector_type(8))) short short8;
typedef __attribute__((ext_vector_type(4))) float f32x4;

__device__ inline void gl_lds16(const void* g, void* l) {
  __builtin_amdgcn_global_load_lds(
      (const __attribute__((address_space(1))) unsigned int*)g,
      (__attribute__((address_space(3))) unsigned int*)l, 16, 0, 0);
}

// fp32 -> bf16 (RNE), 4 elems/thread
__global__ __launch_bounds__(256)
void cvt_bf16(const float4* __restrict__ in, __hip_bfloat162* __restrict__ out,
              int n4) {
  const int i = blockIdx.x * 256 + threadIdx.x;
  if (i < n4) {
    const float4 v = in[i];
    __hip_bfloat162 lo, hi;
    lo.x = __float2bfloat16(v.x); lo.y = __float2bfloat16(v.y);
    hi.x = __float2bfloat16(v.z); hi.y = __float2bfloat16(v.w);
    out[2 * i] = lo;
    out[2 * i + 1] = hi;
  }
}

// ---------------------------------------------------------------------------
// 256x256 8-phase GEMM.  C[m][n] = sum_k A[m][k]*B[n][k], bf16, K-contig both.
// 512 threads = 8 waves (2M x 4N), per-wave 128x64 output, BK=64, LDS 128KiB
// (2 bufs x (A 32K + B 32K)).  Per K-tile: 4 quadrant phases, each
// {ds_read subtile | stage half-tiles -> s_barrier -> setprio(1) -> 16 MFMA ->
//  setprio(0) -> s_barrier}.  Tile t+1 staged during phases 0-1 of tile t
// (into the non-read buffer: race-free), boundary s_waitcnt vmcnt(0) covered
// by ~2.5 phases of MFMA.  LDS bank-conflict fix: 16B-slot XOR swizzle
// slot^=(row&7), applied as inverse-swizzled per-lane GLOBAL source address
// (global_load_lds dest must be linear) + swizzled ds_read address.
// EPI 0: QKV router -> C0=q_ws (ld 2048), C1=k_ws (ld 1024), C2=vT transposed.
// EPI 1: fp32 C row-major, ld = ldc.
// ---------------------------------------------------------------------------
template <int EPI>
__global__ __launch_bounds__(512, 2)
void gemm256(const bf16* __restrict__ A, const bf16* __restrict__ B,
             void* __restrict__ C0, void* __restrict__ C1,
             void* __restrict__ C2, int K, int lda, int ldb, int ldc) {
  extern __shared__ short lds[];
  short* As = lds;            // [2][16384] shorts
  short* Bs = lds + 32768;    // [2][16384] shorts
  const int t = threadIdx.x;
  const int lane = t & 63;
  const int wid = t >> 6, wm = wid >> 2, wn = wid & 3;
  const int m16 = lane & 15, quad = lane >> 4;
  const int brow = blockIdx.y * 256, bcol = blockIdx.x * 256;

  // Staging: thread t -> linear LDS shorts [h*8192 + l*4096 + t*8), which is
  // tile row r = h*128 + l*64 + (t>>3), 16B-slot (t&7).  Source column is
  // inverse-swizzled so that a swizzled READ returns the right data.
  const int srow = t >> 3;                        // 0..63
  const int scol = ((t & 7) ^ (srow & 7)) * 8;    // pre-swizzled src col (elems)
  const bf16* gA[2][2];
  const bf16* gB[2][2];
#pragma unroll
  for (int h = 0; h < 2; ++h)
#pragma unroll
    for (int l = 0; l < 2; ++l) {
      gA[h][l] = A + (size_t)(brow + h * 128 + l * 64 + srow) * lda + scol;
      gB[h][l] = B + (size_t)(bcol + h * 128 + l * 64 + srow) * ldb + scol;
    }
  const int dstoff = t * 8;  // shorts

  // ds_read fragment addressing (row r, k-half k, 16B slot quad):
  //   shorts = r*64 + ((k*4+quad) ^ (r&7))*8 ;  r&7 == m16&7 here.
  const int rbA = (wm * 128 + m16) * 64;
  const int rbB = (wn * 64 + m16) * 64;
  const int sw0 = ((quad) ^ (m16 & 7)) * 8;
  const int sw1 = ((4 + quad) ^ (m16 & 7)) * 8;

  f32x4 acc[8][4] = {};
  short8 a[4][2], b0[2][2], b1[2][2];

  // ---- prologue: stage tile 0 into buf 0, drain, rendezvous ----
#pragma unroll
  for (int h = 0; h < 2; ++h)
#pragma unroll
    for (int l = 0; l < 2; ++l) {
      gl_lds16(gA[h][l], &As[h * 8192 + l * 4096 + dstoff]);
      gl_lds16(gB[h][l], &Bs[h * 8192 + l * 4096 + dstoff]);
    }
  asm volatile("s_waitcnt vmcnt(0)" ::: "memory");
  asm volatile("s_barrier" ::: "memory");

  const int nkt = K >> 6;
  for (int kt = 0; kt < nkt; ++kt) {
    const int buf = kt & 1, nb = (buf ^ 1) * 16384;
    const short* Ab = As + buf * 16384;
    const short* Bb = Bs + buf * 16384;
    const int koff = (kt + 1) << 6;
    const bool pf = (kt + 1) < nkt;

    // ---- phase 0: quadrant (mh0,nh0).  read A(mh0)+B(nh0); stage next A ----
#pragma unroll
    for (int mi = 0; mi < 4; ++mi) {
      a[mi][0] = *(const short8*)&Ab[rbA + mi * 1024 + sw0];
      a[mi][1] = *(const short8*)&Ab[rbA + mi * 1024 + sw1];
    }
#pragma unroll
    for (int ni = 0; ni < 2; ++ni) {
      b0[ni][0] = *(const short8*)&Bb[rbB + ni * 1024 + sw0];
      b0[ni][1] = *(const short8*)&Bb[rbB + ni * 1024 + sw1];
    }
    if (pf) {
#pragma unroll
      for (int h = 0; h < 2; ++h)
#pragma unroll
        for (int l = 0; l < 2; ++l)
          gl_lds16(gA[h][l] + koff, &As[nb + h * 8192 + l * 4096 + dstoff]);
    }
    asm volatile("s_barrier" ::: "memory");
    __builtin_amdgcn_s_setprio(1);
#pragma unroll
    for (int mi = 0; mi < 4; ++mi)
#pragma unroll
      for (int ni = 0; ni < 2; ++ni)
#pragma unroll
        for (int k = 0; k < 2; ++k)
          acc[mi][ni] = __builtin_amdgcn_mfma_f32_16x16x32_bf16(
              a[mi][k], b0[ni][k], acc[mi][ni], 0, 0, 0);
    __builtin_amdgcn_s_setprio(0);
    asm volatile("s_barrier" ::: "memory");

    // ---- phase 1: quadrant (mh0,nh1).  read B(nh1); stage next B ----
#pragma unroll
    for (int ni = 0; ni < 2; ++ni) {
      b1[ni][0] = *(const short8*)&Bb[rbB + (2 + ni) * 1024 + sw0];
      b1[ni][1] = *(const short8*)&Bb[rbB + (2 + ni) * 1024 + sw1];
    }
    if (pf) {
#pragma unroll
      for (int h = 0; h < 2; ++h)
#pragma unroll
        for (int l = 0; l < 2; ++l)
          gl_lds16(gB[h][l] + koff, &Bs[nb + h * 8192 + l * 4096 + dstoff]);
    }
    asm volatile("s_barrier" ::: "memory");
    __builtin_amdgcn_s_setprio(1);
#pragma unroll
    for (int mi = 0; mi < 4; ++mi)
#pragma unroll
      for (int ni = 0; ni < 2; ++ni)
#pragma unroll
        for (int k = 0; k < 2; ++k)
          acc[mi][2 + ni] = __builtin_amdgcn_mfma_f32_16x16x32_bf16(
              a[mi][k], b1[ni][k], acc[mi][2 + ni], 0, 0, 0);
    __builtin_amdgcn_s_setprio(0);
    asm volatile("s_barrier" ::: "memory");

    // ---- phase 2: quadrant (mh1,nh1).  read A(mh1); reuse b1 ----
#pragma unroll
    for (int mi = 0; mi < 4; ++mi) {
      a[mi][0] = *(const short8*)&Ab[rbA + (4 + mi) * 1024 + sw0];
      a[mi][1] = *(const short8*)&Ab[rbA + (4 + mi) * 1024 + sw1];
    }
    asm volatile("s_barrier" ::: "memory");
    __builtin_amdgcn_s_setprio(1);
#pragma unroll
    for (int mi = 0; mi < 4; ++mi)
#pragma unroll
      for (int ni = 0; ni < 2; ++ni)
#pragma unroll
        for (int k = 0; k < 2; ++k)
          acc[4 + mi][2 + ni] = __builtin_amdgcn_mfma_f32_16x16x32_bf16(
              a[mi][k], b1[ni][k], acc[4 + mi][2 + ni], 0, 0, 0);
    __builtin_amdgcn_s_setprio(0);
    asm volatile("s_barrier" ::: "memory");

    // ---- phase 3: quadrant (mh1,nh0).  no reads (a,b0 live); boundary ----
    __builtin_amdgcn_s_setprio(1);
#pragma unroll
    for (int mi = 0; mi < 4; ++mi)
#pragma unroll
      for (int ni = 0; ni < 2; ++ni)
#pragma unroll
        for (int k = 0; k < 2; ++k)
          acc[4 + mi][ni] = __builtin_amdgcn_mfma_f32_16x16x32_bf16(
              a[mi][k], b0[ni][k], acc[4 + mi][ni], 0, 0, 0);
    __builtin_amdgcn_s_setprio(0);
    // next tile's loads (issued phases 0-1, ~2.5 phases ago) must have landed
    asm volatile("s_waitcnt vmcnt(0)" ::: "memory");
    asm volatile("s_barrier" ::: "memory");
  }

  // ---- epilogue ----
  const int row0 = brow + wm * 128 + quad * 4;
  const int col0 = bcol + wn * 64 + m16;
#pragma unroll
  for (int mi = 0; mi < 8; ++mi) {
#pragma unroll
    for (int ni = 0; ni < 4; ++ni) {
      const int col = col0 + ni * 16;
#pragma unroll
      for (int r = 0; r < 4; ++r) {
        const int row = row0 + mi * 16 + r;
        const float v = acc[mi][ni][r];
        if constexpr (EPI == 0) {
          // col tiles are 256-wide; 2048/3072 boundaries are block-uniform
          if (col < 2048) {
            ((bf16*)C0)[(size_t)row * 2048 + col] = __float2bfloat16(v);
          } else if (col < 3072) {
            ((bf16*)C1)[(size_t)row * 1024 + (col - 2048)] = __float2bfloat16(v);
          } else {
            const int b = row >> 11;
            ((bf16*)C2)[((size_t)(b * 1024 + (col - 3072))) * 2048 +
                        (row & 2047)] = __float2bfloat16(v);
          }
        } else {
          ((float*)C0)[(size_t)row * ldc + col] = v;
        }
      }
    }
  }
}

// ---------------------------------------------------------------------------
// 128x128 GEMM (proven m97 structure) - kept for attention-inner matmuls.
// C[m][n] = sum_k A[m][k]*B[n][k], bf16 operands, K-contiguous both sides.
// Grid (N/128, M/128, zh). A += zh*sAh; B += (zh>>1)*sBh; C elem off zh*sCh.
// EPI 0: bf16 C row-major.  EPI 1: fp32 C, scale+softcap (scores).
// ---------------------------------------------------------------------------
template <int EPI>
__global__ __launch_bounds__(256)
void gemm(const bf16* __restrict__ A, const bf16* __restrict__ B,
          void* __restrict__ Cv, int K, int lda, int ldb, int ldc,
          long sAh, long sBh, long sCh, float cscale) {
  __shared__ short As[4096];  // 128 x 32 bf16
  __shared__ short Bs[4096];
  const int t = threadIdx.x, lane = t & 63, w = t >> 6;
  const int zh = blockIdx.z;
  A += (size_t)zh * sAh;
  B += (size_t)(zh >> 1) * sBh;
  const size_t coff = (size_t)zh * sCh;
  const int blockRow = blockIdx.y * 128, blockCol = blockIdx.x * 128;

  const int e = t * 8;
  const int srow = t >> 2, scol = (t & 3) * 8;
  const bf16* gA0 = A + (size_t)(blockRow + srow) * lda + scol;
  const bf16* gA1 = gA0 + (size_t)64 * lda;
  const bf16* gB0 = B + (size_t)(blockCol + srow) * ldb + scol;
  const bf16* gB1 = gB0 + (size_t)64 * ldb;

  const int wm = w >> 1, wn = w & 1;
  const int quad = lane >> 4, m16 = lane & 15;
  f32x4 acc[4][4] = {};

  for (int kt = 0; kt < K; kt += 32) {
    __syncthreads();
    gl_lds16(gA0 + kt, &As[e]);
    gl_lds16(gA1 + kt, &As[e + 2048]);
    gl_lds16(gB0 + kt, &Bs[e]);
    gl_lds16(gB1 + kt, &Bs[e + 2048]);
    __syncthreads();
    short8 af[4], bfr[4];
#pragma unroll
    for (int i = 0; i < 4; ++i)
      af[i] = *(const short8*)&As[(wm * 64 + i * 16 + m16) * 32 + quad * 8];
#pragma unroll
    for (int j = 0; j < 4; ++j)
      bfr[j] = *(const short8*)&Bs[(wn * 64 + j * 16 + m16) * 32 + quad * 8];
#pragma unroll
    for (int i = 0; i < 4; ++i)
#pragma unroll
      for (int j = 0; j < 4; ++j)
        acc[i][j] = __builtin_amdgcn_mfma_f32_16x16x32_bf16(af[i], bfr[j],
                                                            acc[i][j], 0, 0, 0);
  }

#pragma unroll
  for (int i = 0; i < 4; ++i) {
#pragma unroll
    for (int j = 0; j < 4; ++j) {
      const int gcol = blockCol + wn * 64 + j * 16 + m16;
#pragma unroll
      for (int r = 0; r < 4; ++r) {
        const int grow = blockRow + wm * 64 + i * 16 + quad * 4 + r;
        float v = acc[i][j][r] * cscale;
        if constexpr (EPI == 1) {
          // softcap 50*tanh(v/50) via expf; mask zeros, window structural
          const float y = v * 0.02f;
          const float ee = __expf(-2.0f * fabsf(y));
          v = copysignf(50.0f * (1.0f - ee) / (1.0f + ee), y);
          ((float*)Cv)[coff + (size_t)grow * ldc + gcol] = v;
        } else {
          ((bf16*)Cv)[coff + (size_t)grow * ldc + gcol] = __float2bfloat16(v);
        }
      }
    }
  }
}

// One wave per 256-elem head vector, in place. hmod: heads per token row.
__global__ __launch_bounds__(256)
void norm_rope(bf16* __restrict__ qk, const float* __restrict__ nw, int hmod) {
  const int seg = blockIdx.x * 4 + (threadIdx.x >> 6);
  const int lane = threadIdx.x & 63;
  bf16* p = qk + (size_t)seg * 256;
  float x0 = __bfloat162float(p[lane]);
  float x1 = __bfloat162float(p[lane + 64]);
  float x2 = __bfloat162float(p[lane + 128]);
  float x3 = __bfloat162float(p[lane + 192]);
  float ss = x0 * x0 + x1 * x1 + x2 * x2 + x3 * x3;
#pragma unroll
  for (int o = 32; o; o >>= 1) ss += __shfl_xor(ss, o);
  const float r = rsqrtf(ss * (1.0f / 256.0f) + 1e-6f);
  const float n0 = x0 * r * (1.0f + nw[lane]);
  const float n1 = x1 * r * (1.0f + nw[lane + 64]);
  const float n2 = x2 * r * (1.0f + nw[lane + 128]);
  const float n3 = x3 * r * (1.0f + nw[lane + 192]);
  const int l = (seg / hmod) & 2047;
  const float kf = -9.210340371976184f / 128.0f;  // -ln(10000)/128
  float c0, s0, c1, s1;
  sincosf((float)l * expf(kf * (float)lane), &s0, &c0);
  sincosf((float)l * expf(kf * (float)(lane + 64)), &s1, &c1);
  p[lane]       = __float2bfloat16(n0 * c0 - n2 * s0);
  p[lane + 128] = __float2bfloat16(n2 * c0 + n0 * s0);
  p[lane + 64]  = __float2bfloat16(n1 * c1 - n3 * s1);
  p[lane + 192] = __float2bfloat16(n3 * c1 + n1 * s1);
}

// One wave per 512-wide fp32 score row; bf16 P written IN PLACE (row stride
// 1024 bf16 elems).
__global__ __launch_bounds__(256)
void softmax_k(float* __restrict__ S) {
  const int row = blockIdx.x * 4 + (threadIdx.x >> 6);
  const int lane = threadIdx.x & 63;
  float* rowp = S + (size_t)row * 512;
  const float4 a = ((const float4*)rowp)[lane];
  const float4 b = ((const float4*)rowp)[lane + 64];
  float mx = fmaxf(fmaxf(fmaxf(a.x, a.y), fmaxf(a.z, a.w)),
                   fmaxf(fmaxf(b.x, b.y), fmaxf(b.z, b.w)));
#pragma unroll
  for (int o = 32; o; o >>= 1) mx = fmaxf(mx, __shfl_xor(mx, o));
  float e0 = expf(a.x - mx), e1 = expf(a.y - mx);
  float e2 = expf(a.z - mx), e3 = expf(a.w - mx);
  float f0 = expf(b.x - mx), f1 = expf(b.y - mx);
  float f2 = expf(b.z - mx), f3 = expf(b.w - mx);
  float sum = e0 + e1 + e2 + e3 + f0 + f1 + f2 + f3;
#pragma unroll
  for (int o = 32; o; o >>= 1) sum += __shfl_xor(sum, o);
  const float inv = 1.0f / sum;
  bf16* p0 = (bf16*)rowp + lane * 4;
  p0[0] = __float2bfloat16(e0 * inv);
  p0[1] = __float2bfloat16(e1 * inv);
  p0[2] = __float2bfloat16(e2 * inv);
  p0[3] = __float2bfloat16(e3 * inv);
  bf16* p1 = p0 + 256;
  p1[0] = __float2bfloat16(f0 * inv);
  p1[1] = __float2bfloat16(f1 * inv);
  p1[2] = __float2bfloat16(f2 * inv);
  p1[3] = __float2bfloat16(f3 * inv);
}

extern "C" void kernel_launch(void* const* d_in, const int* in_sizes, int n_in,
                              void* d_out, int out_size, void* d_ws, size_t ws_size,
                              hipStream_t stream) {
  const float* x    = (const float*)d_in[0];
  const float* q_w  = (const float*)d_in[2];
  const float* k_w  = (const float*)d_in[3];
  const float* v_w  = (const float*)d_in[4];
  const float* o_w  = (const float*)d_in[5];
  const float* q_nw = (const float*)d_in[6];
  const float* k_nw = (const float*)d_in[7];
  float* out = (float*)d_out;

  char* wsb = (char*)d_ws;
  bf16* xb    = (bf16*)(wsb);             // 4096x2560
  float* sc   = (float*)(wsb);            // aliases xb after projections
  bf16* qkvwb = (bf16*)(wsb + 20971520);  // 4096x2560 (q 0-2047|k|v rows)
  bf16* owb   = qkvwb;                    // aliases q-rows after QKV proj
  bf16* kwb   = (bf16*)(wsb + 31457280);  // rows 2048-3071
  bf16* vwb   = (bf16*)(wsb + 36700160);  // rows 3072-4095
  bf16* q_ws  = (bf16*)(wsb + 41943040);  // 4096x2048
  bf16* k_ws  = (bf16*)(wsb + 58720256);  // 4096x1024
  bf16* vT    = (bf16*)(wsb + 67108864);  // (b,kvh,d)x2048
  bf16* attn  = q_ws;  // PV(b,c) writes exactly the cols scores(b,c) consumed

  static bool attr_set = false;
  if (!attr_set) {
    (void)hipFuncSetAttribute(reinterpret_cast<const void*>(&gemm256<0>),
                              hipFuncAttributeMaxDynamicSharedMemorySize, 131072);
    (void)hipFuncSetAttribute(reinterpret_cast<const void*>(&gemm256<1>),
                              hipFuncAttributeMaxDynamicSharedMemorySize, 131072);
    attr_set = true;
  }

  dim3 blk(256);
  // fp32 -> bf16 operand copies (q|k|v weight rows land contiguously)
  cvt_bf16<<<dim3(10240), blk, 0, stream>>>((const float4*)x,   (__hip_bfloat162*)xb,    2621440);
  cvt_bf16<<<dim3(5120),  blk, 0, stream>>>((const float4*)q_w, (__hip_bfloat162*)qkvwb, 1310720);
  cvt_bf16<<<dim3(2560),  blk, 0, stream>>>((const float4*)k_w, (__hip_bfloat162*)kwb,   655360);
  cvt_bf16<<<dim3(2560),  blk, 0, stream>>>((const float4*)v_w, (__hip_bfloat162*)vwb,   655360);
  // fused QKV projection: M=4096, N=4096 (q|k|v), K=2560 -> 16x16=256 blocks
  gemm256<0><<<dim3(16, 16), dim3(512), 131072, stream>>>(
      xb, qkvwb, (void*)q_ws, (void*)k_ws, (void*)vT, 2560, 2560, 2560, 0);
  // o_w -> bf16 into q-weight region (QKV done; stream-ordered)
  cvt_bf16<<<dim3(5120), blk, 0, stream>>>((const float4*)o_w, (__hip_bfloat162*)owb, 1310720);
  // RMSNorm + RoPE in place
  norm_rope<<<dim3(8192), blk, 0, stream>>>(q_ws, q_nw, 8);
  norm_rope<<<dim3(4096), blk, 0, stream>>>(k_ws, k_nw, 4);
  // attention per (batch b, 4-head chunk c); sc aliases xb (projections done)
  for (int b = 0; b < 2; ++b) {
    for (int c = 0; c < 2; ++c) {
      // scores: M=2048, N=512 keys (1536..2047), K=256
      gemm<1><<<dim3(4, 16, 4), blk, 0, stream>>>(
          q_ws + (size_t)b * 4194304 + c * 1024,
          k_ws + (size_t)b * 2097152 + 1572864 + c * 512,
          (void*)sc, 256, 2048, 1024, 512,
          256L, 256L, 1048576L, 1.0f / 16.0f);
      softmax_k<<<dim3(2048), blk, 0, stream>>>(sc);
      // attn = P@V: M=2048, N=256, K=512; P row stride 1024; vT ld 2048
      gemm<0><<<dim3(2, 16, 4), blk, 0, stream>>>(
          (const bf16*)sc,
          vT + (size_t)b * 2097152 + (size_t)c * 1048576 + 1536,
          (void*)(attn + (size_t)b * 4194304 + c * 1024), 512, 1024, 2048, 2048,
          2097152L, 524288L, 256L, 1.0f);
    }
  }
  // out = attn @ o_w^T : M=4096, N=2560, K=2048, fp32 store (10x16=160 blocks)
  gemm256<1><<<dim3(10, 16), dim3(512), 131072, stream>>>(
      attn, owb, (void*)out, nullptr, nullptr, 2048, 2048, 2048, 2560);
}